// Round 13
// baseline (282.598 us; speedup 1.0000x reference)
//
#include <hip/hip_runtime.h>

#define NN 20000
#define NEDGE 320000
#define COORD_MAX 10.0f

#define LDH 136    // ushort stride (272B, 16B-aligned)
#define TILE_N 64
#define LDN  264   // node kernel input stride (K=256)

typedef __attribute__((ext_vector_type(4))) float f32x4;
typedef __attribute__((ext_vector_type(8))) short short8;
typedef __attribute__((ext_vector_type(8))) __bf16 bf16x8;

static __device__ __forceinline__ f32x4 mfma16(short8 a, short8 b, f32x4 c) {
  return __builtin_amdgcn_mfma_f32_16x16x32_bf16(
      __builtin_bit_cast(bf16x8, a), __builtin_bit_cast(bf16x8, b), c, 0, 0, 0);
}
static __device__ __forceinline__ float bf2f(unsigned short u) {
  unsigned x = ((unsigned)u) << 16;
  return __builtin_bit_cast(float, x);
}
// packed f32x2 -> bf16x2 (RNE), 1 VALU op (gfx950)
static __device__ __forceinline__ unsigned cvtpk(float lo, float hi) {
  unsigned r;
  asm("v_cvt_pk_bf16_f32 %0, %1, %2" : "=v"(r) : "v"(lo), "v"(hi));
  return r;
}
static __device__ __forceinline__ float sigm(float x) {
  return __builtin_amdgcn_rcpf(1.f + __expf(-x));
}
static __device__ __forceinline__ float silu_(float x) { return x * sigm(x); }

// ---------------------------------------------------------------------------
// Prep uber-kernel, grid (1250, 3):
// y=0: edge histogram; y=1: zero agg accumulators; y=2: the 11 weight packs
// (flattened over blockIdx.x via cumulative block offsets).
// ---------------------------------------------------------------------------
struct PackJobs {
  const float* w[11];
  unsigned short* o[11];
  int kreal[11];
  int nk[11];
};

__global__ void egnn_prep(PackJobs J,
                          const int* __restrict__ eTgt, const int* __restrict__ eSrc,
                          int* __restrict__ cntT, int* __restrict__ cntS,
                          float* __restrict__ aggZero /* 2*NN*128 floats */) {
  const int y = blockIdx.y;
  const int tid = threadIdx.x;
  if (y == 0) {
    const int idx = blockIdx.x * 256 + tid;
    if (idx < NEDGE) {
      atomicAdd(&cntT[eTgt[idx]], 1);
      atomicAdd(&cntS[eSrc[idx]], 1);
    }
  } else if (y == 1) {
    float4* p = reinterpret_cast<float4*>(aggZero);
    const int total = 2 * NN * 128 / 4;
    for (int k = blockIdx.x * 256 + tid; k < total; k += 1250 * 256)
      p[k] = float4{0.f, 0.f, 0.f, 0.f};
  } else {
    // flattened pack jobs: job j needs nk[j]*2 blocks of 256
    int gidx = blockIdx.x;
    int j = 0, base = 0;
    while (j < 11 && gidx >= base + J.nk[j] * 2) { base += J.nk[j] * 2; ++j; }
    if (j >= 11) return;
    const int idx = (gidx - base) * 256 + tid;
    const float* w = J.w[j];
    const int kreal = J.kreal[j];
    const int lane = idx & 63;
    const int ct = (idx >> 6) & 7;
    const int kstep = idx >> 9;
    const int col = ct * 16 + (lane & 15);
    const int k0 = kstep * 32 + (lane >> 4) * 8;
    float v[8];
#pragma unroll
    for (int k = 0; k < 8; ++k) {
      int kk = k0 + k;
      v[k] = (kk < kreal) ? w[(size_t)kk * 128 + col] : 0.f;
    }
    uint4 pk = {cvtpk(v[0], v[1]), cvtpk(v[2], v[3]),
                cvtpk(v[4], v[5]), cvtpk(v[6], v[7])};
    reinterpret_cast<uint4*>(J.o[j])[idx] = pk;
  }
}

// ---------------------------------------------------------------------------
// Precompute (+ fused scan as job 2):
// job0 (src): S1A = srcF@w1topA, S1B = srcF@w1topB.
// job1 (tgt): T1A = tgtF@w1midA + b1A, T1B = ... + b1B.
// job2, blockIdx.x<2: exclusive scan of cntT/cntS -> rowptr + off.
// ---------------------------------------------------------------------------
struct PreJobs {
  const float* x[2];
  const unsigned short* wA[2];
  const unsigned short* wB[2];
  const float* biasA[2];   // null -> none
  const float* biasB[2];
  unsigned short* oA[2];
  unsigned short* oB[2];
};

__global__ __launch_bounds__(256, 4) void egnn_pre(
    PreJobs J, int N,
    const int* __restrict__ c0, int* __restrict__ r0, int* __restrict__ o0,
    const int* __restrict__ c1, int* __restrict__ r1, int* __restrict__ o1) {
  __shared__ __align__(16) unsigned short sX[64 * LDH];
  __shared__ int sums[256];
  const int job = blockIdx.y;
  const int tid = threadIdx.x;

  if (job == 2) {
    if (blockIdx.x >= 2) return;
    const int* cnt = blockIdx.x ? c1 : c0;
    int* rp = blockIdx.x ? r1 : r0;
    int* oc = blockIdx.x ? o1 : o0;
    const int chunk = (NN + 255) / 256;
    const int i0 = tid * chunk;
    int local = 0;
    for (int k = 0; k < chunk; ++k) {
      const int i = i0 + k;
      if (i < NN) local += cnt[i];
    }
    sums[tid] = local;
    __syncthreads();
    for (int s = 1; s < 256; s <<= 1) {
      int v = (tid >= s) ? sums[tid - s] : 0;
      __syncthreads();
      sums[tid] += v;
      __syncthreads();
    }
    int run = (tid == 0) ? 0 : sums[tid - 1];
    for (int k = 0; k < chunk; ++k) {
      const int i = i0 + k;
      if (i < NN) { rp[i] = run; oc[i] = run; run += cnt[i]; }
    }
    if (tid == 255) rp[NN] = sums[255];
    return;
  }

  const float* __restrict__ X = J.x[job];
  const int n0 = blockIdx.x * 64;

  for (int s = tid; s < 64 * 32; s += 256) {
    const int row = s >> 5;
    const int c4 = (s & 31) * 4;
    const int node = n0 + row;
    float4 v = {0.f, 0.f, 0.f, 0.f};
    if (node < N) v = reinterpret_cast<const float4*>(X + (size_t)node * 128)[s & 31];
    *reinterpret_cast<uint2*>(&sX[row * LDH + c4]) =
        uint2{cvtpk(v.x, v.y), cvtpk(v.z, v.w)};
  }
  __syncthreads();

  const int lane = tid & 63, wid = tid >> 6;
  const int r16 = lane & 15, g4 = lane >> 4;
  const int rowBase = wid * 16;

#pragma unroll 1
  for (int half = 0; half < 2; ++half) {
    const unsigned short* __restrict__ W = half ? J.wB[job] : J.wA[job];
    const float* __restrict__ bias = half ? J.biasB[job] : J.biasA[job];
    unsigned short* __restrict__ O = half ? J.oB[job] : J.oA[job];
    f32x4 acc[8];
#pragma unroll
    for (int ct = 0; ct < 8; ++ct) acc[ct] = f32x4{0.f, 0.f, 0.f, 0.f};
#pragma unroll
    for (int ks = 0; ks < 4; ++ks) {
      const short8 a = *reinterpret_cast<const short8*>(
          &sX[(rowBase + r16) * LDH + ks * 32 + g4 * 8]);
#pragma unroll
      for (int ct = 0; ct < 8; ++ct) {
        const short8 b = *reinterpret_cast<const short8*>(
            W + ((size_t)(ks * 8 + ct) * 64 + lane) * 8);
        acc[ct] = mfma16(a, b, acc[ct]);
      }
    }
#pragma unroll
    for (int ct = 0; ct < 8; ct += 2) {
      const int col0 = ct * 16 + r16;
      const int col1 = col0 + 16;
      const float bv0 = bias ? bias[col0] : 0.f;
      const float bv1 = bias ? bias[col1] : 0.f;
#pragma unroll
      for (int r = 0; r < 4; ++r) {
        const int node = n0 + rowBase + g4 * 4 + r;
        if (node < N) {
          const unsigned pk = cvtpk(acc[ct][r] + bv0, acc[ct + 1][r] + bv1);
          O[(size_t)node * 128 + col0] = (unsigned short)pk;
          O[(size_t)node * 128 + col1] = (unsigned short)(pk >> 16);
        }
      }
    }
  }
}

// ---------------------------------------------------------------------------
// Scatter: write SORTED (s,t) pairs directly.
// ---------------------------------------------------------------------------
__global__ void egnn_scatter(const int* __restrict__ eTgt, const int* __restrict__ eSrc,
                             int* __restrict__ offT, int* __restrict__ offS,
                             int2* __restrict__ stT, int2* __restrict__ stS) {
  const int e = blockIdx.x * 256 + threadIdx.x;
  if (e < NEDGE) {
    const int s = eSrc[e], t = eTgt[e];
    stT[atomicAdd(&offT[t], 1)] = int2{s, t};
    stS[atomicAdd(&offS[s], 1)] = int2{s, t};
  }
}

// ---------------------------------------------------------------------------
// Fused edge kernel, sorted order (round-10 structure + ballot segreduce +
// setprio around MFMA clusters). 128 edges/block, 4 waves x 32 edges,
// dir = blockIdx.y. h-build with 16-load register prefetch (16B gathers).
// Segment boundaries computed ONCE per wave via __ballot -> scalar branch.
// ---------------------------------------------------------------------------
__global__ __launch_bounds__(256, 4) void egnn_edge(
    const unsigned short* __restrict__ S1A, const unsigned short* __restrict__ T1A,
    const unsigned short* __restrict__ S1B, const unsigned short* __restrict__ T1B,
    const float* __restrict__ srcC, const float* __restrict__ tgtC,
    const int2* __restrict__ stT, const int2* __restrict__ stS,
    const float* __restrict__ w1A, const float* __restrict__ w1B,  // radial rows
    const unsigned short* __restrict__ w2pA, const float* __restrict__ b2A,
    const float* __restrict__ wgA, const float* __restrict__ bgA,
    const unsigned short* __restrict__ w2pB, const float* __restrict__ b2B,
    const float* __restrict__ wgB, const float* __restrict__ bgB,
    const unsigned short* __restrict__ wc1p, const float* __restrict__ bc1,
    const float* __restrict__ wc2,
    float* __restrict__ aggA, float* __restrict__ aggB,
    float* __restrict__ wtBuf)
{
  __shared__ __align__(16) unsigned short sH[4][32 * LDH];  // 34816 B
  __shared__ float sCD[128 * 3];
  __shared__ float sRad[128];
  __shared__ int sS[128];
  __shared__ int sT[128];

  const int dir = blockIdx.y;
  const int tid = threadIdx.x;
  const int j0 = blockIdx.x * 128;

  if (tid < 128) {
    const int2 st = (dir ? stS : stT)[j0 + tid];
    const int s = st.x, t = st.y;
    sS[tid] = s; sT[tid] = t;
    const float dx = tgtC[t * 3 + 0] - srcC[s * 3 + 0];
    const float dy = tgtC[t * 3 + 1] - srcC[s * 3 + 1];
    const float dz = tgtC[t * 3 + 2] - srcC[s * 3 + 2];
    if (dir == 0) {
      sCD[tid * 3 + 0] = dx; sCD[tid * 3 + 1] = dy; sCD[tid * 3 + 2] = dz;
    }
    sRad[tid] = dx * dx + dy * dy + dz * dz;
  }
  __syncthreads();

  const int lane = tid & 63, wid = tid >> 6;
  const int r16 = lane & 15, g4 = lane >> 4;
  const int we = wid * 32;
  const int c8 = (lane & 15) * 8;   // 16B gather column offset
  const int r4 = lane >> 4;         // 0..3: row within 4-row group
  const int c2 = lane * 2;

  const unsigned short* __restrict__ S1 = dir ? S1B : S1A;
  const unsigned short* __restrict__ T1 = dir ? T1B : T1A;  // bias folded in
  const float* w1 = dir ? w1B : w1A;
  const float4 wr0 = *reinterpret_cast<const float4*>(w1 + 256 * 128 + c8);
  const float4 wr1 = *reinterpret_cast<const float4*>(w1 + 256 * 128 + c8 + 4);
  const float* b2 = dir ? b2B : b2A;
  const float* wg = dir ? wgB : wgA;
  const float bg = dir ? bgB[0] : bgA[0];
  const int* __restrict__ nids = dir ? sS : sT;
  float* __restrict__ agg = dir ? aggB : aggA;

  // segment-boundary mask for this wave's 32 rows (wave-uniform, one ballot):
  // bit `row` set  <=>  row is the LAST row of its node segment.
  const unsigned long long bmask =
      __ballot(lane >= 31 || nids[we + ((lane + 1) & 31)] != nids[we + (lane & 31)]);

  unsigned short* hT = sH[wid];

  // ---- h-build: issue ALL 16 gathers first (register prefetch), then compute
  {
    short8 gA[2][4], gB[2][4];
#pragma unroll
    for (int c = 0; c < 2; ++c)
#pragma unroll
      for (int i = 0; i < 4; ++i) {
        const int row = (c * 4 + i) * 4 + r4;
        const int e = we + row;
        gA[c][i] = *reinterpret_cast<const short8*>(S1 + (size_t)sS[e] * 128 + c8);
        gB[c][i] = *reinterpret_cast<const short8*>(T1 + (size_t)sT[e] * 128 + c8);
      }
#pragma unroll
    for (int c = 0; c < 2; ++c)
#pragma unroll
      for (int i = 0; i < 4; ++i) {
        const int row = (c * 4 + i) * 4 + r4;
        const int e = we + row;
        const float rad = sRad[e];
        union { short8 v; unsigned short u[8]; } a, b;
        a.v = gA[c][i]; b.v = gB[c][i];
        const float f0 = silu_(bf2f(a.u[0]) + bf2f(b.u[0]) + rad * wr0.x);
        const float f1 = silu_(bf2f(a.u[1]) + bf2f(b.u[1]) + rad * wr0.y);
        const float f2 = silu_(bf2f(a.u[2]) + bf2f(b.u[2]) + rad * wr0.z);
        const float f3 = silu_(bf2f(a.u[3]) + bf2f(b.u[3]) + rad * wr0.w);
        const float f4 = silu_(bf2f(a.u[4]) + bf2f(b.u[4]) + rad * wr1.x);
        const float f5 = silu_(bf2f(a.u[5]) + bf2f(b.u[5]) + rad * wr1.y);
        const float f6 = silu_(bf2f(a.u[6]) + bf2f(b.u[6]) + rad * wr1.z);
        const float f7 = silu_(bf2f(a.u[7]) + bf2f(b.u[7]) + rad * wr1.w);
        *reinterpret_cast<uint4*>(&hT[row * LDH + c8]) =
            uint4{cvtpk(f0, f1), cvtpk(f2, f3), cvtpk(f4, f5), cvtpk(f6, f7)};
      }
  }

  // ---- GEMM2: 2 row-tiles x [16x128] @ [128x128]
  const unsigned short* w2p = dir ? w2pB : w2pA;
  f32x4 acc[2][8];
#pragma unroll
  for (int rt = 0; rt < 2; ++rt)
#pragma unroll
    for (int ct = 0; ct < 8; ++ct) acc[rt][ct] = f32x4{0.f, 0.f, 0.f, 0.f};
  __builtin_amdgcn_s_setprio(1);
#pragma unroll
  for (int ks = 0; ks < 4; ++ks) {
    short8 a[2];
#pragma unroll
    for (int rt = 0; rt < 2; ++rt)
      a[rt] = *reinterpret_cast<const short8*>(
          &hT[(rt * 16 + r16) * LDH + ks * 32 + g4 * 8]);
#pragma unroll
    for (int ct = 0; ct < 8; ++ct) {
      const short8 b = *reinterpret_cast<const short8*>(
          w2p + ((size_t)(ks * 8 + ct) * 64 + lane) * 8);
#pragma unroll
      for (int rt = 0; rt < 2; ++rt) acc[rt][ct] = mfma16(a[rt], b, acc[rt][ct]);
    }
  }
  __builtin_amdgcn_s_setprio(0);

  // ---- bias + SiLU + gate
  float part[2][4];
#pragma unroll
  for (int rt = 0; rt < 2; ++rt)
#pragma unroll
    for (int r = 0; r < 4; ++r) part[rt][r] = 0.f;
#pragma unroll
  for (int ct = 0; ct < 8; ++ct) {
    const float b2v = b2[ct * 16 + r16];
    const float wgv = wg[ct * 16 + r16];
#pragma unroll
    for (int rt = 0; rt < 2; ++rt)
#pragma unroll
      for (int r = 0; r < 4; ++r) {
        const float e = silu_(acc[rt][ct][r] + b2v);
        acc[rt][ct][r] = e;
        part[rt][r] += e * wgv;
      }
  }
#pragma unroll
  for (int m = 1; m < 16; m <<= 1)
#pragma unroll
    for (int rt = 0; rt < 2; ++rt)
#pragma unroll
      for (int r = 0; r < 4; ++r) part[rt][r] += __shfl_xor(part[rt][r], m, 64);
#pragma unroll
  for (int rt = 0; rt < 2; ++rt)
#pragma unroll
    for (int r = 0; r < 4; ++r) {
      const float gate = sigm(part[rt][r] + bg);
#pragma unroll
      for (int ct = 0; ct < 8; ++ct) acc[rt][ct][r] *= gate;
    }

  if (dir == 0) {
    // ---- scalar-transposed stash (row = edge, col = TRUE feature), cvtpk-paired
#pragma unroll
    for (int rt = 0; rt < 2; ++rt)
#pragma unroll
      for (int ct = 0; ct < 8; ct += 2)
#pragma unroll
        for (int r = 0; r < 4; ++r) {
          const int row = rt * 16 + g4 * 4 + r;
          const unsigned pk = cvtpk(acc[rt][ct][r], acc[rt][ct + 1][r]);
          hT[row * LDH + ct * 16 + r16] = (unsigned short)pk;
          hT[row * LDH + (ct + 1) * 16 + r16] = (unsigned short)(pk >> 16);
        }

    // ---- coord GEMM on gated e_s2t
    f32x4 ac[2][8];
#pragma unroll
    for (int rt = 0; rt < 2; ++rt)
#pragma unroll
      for (int ct = 0; ct < 8; ++ct) ac[rt][ct] = f32x4{0.f, 0.f, 0.f, 0.f};
    __builtin_amdgcn_s_setprio(1);
#pragma unroll
    for (int ks = 0; ks < 4; ++ks) {
      short8 a[2];
#pragma unroll
      for (int rt = 0; rt < 2; ++rt)
        a[rt] = *reinterpret_cast<const short8*>(
            &hT[(rt * 16 + r16) * LDH + ks * 32 + g4 * 8]);
#pragma unroll
      for (int ct = 0; ct < 8; ++ct) {
        const short8 b = *reinterpret_cast<const short8*>(
            wc1p + ((size_t)(ks * 8 + ct) * 64 + lane) * 8);
#pragma unroll
        for (int rt = 0; rt < 2; ++rt) ac[rt][ct] = mfma16(a[rt], b, ac[rt][ct]);
      }
    }
    __builtin_amdgcn_s_setprio(0);
    float pc[2][4];
#pragma unroll
    for (int rt = 0; rt < 2; ++rt)
#pragma unroll
      for (int r = 0; r < 4; ++r) pc[rt][r] = 0.f;
#pragma unroll
    for (int ct = 0; ct < 8; ++ct) {
      const float bcv = bc1[ct * 16 + r16];
      const float w2v = wc2[ct * 16 + r16];
#pragma unroll
      for (int rt = 0; rt < 2; ++rt)
#pragma unroll
        for (int r = 0; r < 4; ++r)
          pc[rt][r] += silu_(ac[rt][ct][r] + bcv) * w2v;
    }
#pragma unroll
    for (int m = 1; m < 16; m <<= 1)
#pragma unroll
      for (int rt = 0; rt < 2; ++rt)
#pragma unroll
        for (int r = 0; r < 4; ++r) pc[rt][r] += __shfl_xor(pc[rt][r], m, 64);

#pragma unroll
    for (int rt = 0; rt < 2; ++rt)
#pragma unroll
      for (int r = 0; r < 4; ++r) {
        if (r16 == 0) {
          const int el = we + rt * 16 + g4 * 4 + r;
          const float p = pc[rt][r];
          const float4 w = {sCD[el * 3 + 0] * p, sCD[el * 3 + 1] * p,
                            sCD[el * 3 + 2] * p, 0.f};
          *reinterpret_cast<float4*>(wtBuf + (size_t)(j0 + el) * 4) = w;
        }
      }

    // ---- segreduce (true-col layout), ballot-mask boundaries (scalar branch)
    float s0 = 0.f, s1 = 0.f;
    int segStart = 0;
#pragma unroll 4
    for (int row = 0; row < 32; ++row) {
      const ushort2 v = *reinterpret_cast<const ushort2*>(&hT[row * LDH + c2]);
      s0 += bf2f(v.x); s1 += bf2f(v.y);
      if (bmask & (1ull << row)) {
        const int node = nids[we + row];
        float* dst = agg + (size_t)node * 128 + c2;
        if (segStart > 0 && row < 31) {
          dst[0] = s0; dst[1] = s1;
        } else {
          atomicAdd(dst, s0);
          atomicAdd(dst + 1, s1);
        }
        s0 = 0.f; s1 = 0.f;
        segStart = row + 1;
      }
    }
  } else {
    // ---- packed col'-layout stash: one 16B write per (rt, r)
    // position p = r16*8 + ct  (true col = ct*16 + r16)
#pragma unroll
    for (int rt = 0; rt < 2; ++rt)
#pragma unroll
      for (int r = 0; r < 4; ++r) {
        const int row = rt * 16 + g4 * 4 + r;
        const uint4 pk = {cvtpk(acc[rt][0][r], acc[rt][1][r]),
                          cvtpk(acc[rt][2][r], acc[rt][3][r]),
                          cvtpk(acc[rt][4][r], acc[rt][5][r]),
                          cvtpk(acc[rt][6][r], acc[rt][7][r])};
        *reinterpret_cast<uint4*>(&hT[row * LDH + r16 * 8]) = pk;
      }

    // ---- permuted segreduce, ballot-mask boundaries
    // true cols: t0 = ((2*lane)&7)*16 + (lane>>2), t1 = t0 + 16
    const int t0 = ((2 * lane) & 7) * 16 + (lane >> 2);
    float s0 = 0.f, s1 = 0.f;
    int segStart = 0;
#pragma unroll 4
    for (int row = 0; row < 32; ++row) {
      const ushort2 v = *reinterpret_cast<const ushort2*>(&hT[row * LDH + c2]);
      s0 += bf2f(v.x); s1 += bf2f(v.y);
      if (bmask & (1ull << row)) {
        const int node = nids[we + row];
        float* dst = agg + (size_t)node * 128;
        if (segStart > 0 && row < 31) {
          dst[t0] = s0; dst[t0 + 16] = s1;
        } else {
          atomicAdd(dst + t0, s0);
          atomicAdd(dst + t0 + 16, s1);
        }
        s0 = 0.f; s1 = 0.f;
        segStart = row + 1;
      }
    }
  }
}

// ---------------------------------------------------------------------------
// Node kernel (+ fused coord finalize as job 2). sH2 aliases sIn (barrier
// separates the last sIn read from sH2 writes) -> 33.8 KB LDS, 4 blocks/CU.
// ---------------------------------------------------------------------------
struct NodeJobs {
  const float* feat[2];
  const float* agg[2];
  const unsigned short* w1p[2];
  const float* b1[2];
  const unsigned short* w2p[2];
  const float* b2[2];
  float* outp[2];
};

__global__ __launch_bounds__(256, 4) void egnn_node(
    NodeJobs J, int N,
    const float* __restrict__ srcC, const float* __restrict__ tgtC,
    const float* __restrict__ wt, const int* __restrict__ rp,
    float* __restrict__ outSC, float* __restrict__ outTC) {
  __shared__ __align__(16) unsigned short sIn[TILE_N * LDN];  // 33792 B
  unsigned short* sH2 = sIn;  // aliased; safe after barrier below
  const int job = blockIdx.y;
  const int tid = threadIdx.x;

  if (job == 2) {
    const int n = blockIdx.x * 256 + tid;
    if (n < NN) {
      outSC[n * 3 + 0] = srcC[n * 3 + 0];
      outSC[n * 3 + 1] = srcC[n * 3 + 1];
      outSC[n * 3 + 2] = srcC[n * 3 + 2];
      const int j0 = rp[n], j1 = rp[n + 1];
      float ax = 0.f, ay = 0.f, az = 0.f;
      for (int j = j0; j < j1; ++j) {
        const float4 v = *reinterpret_cast<const float4*>(wt + (size_t)j * 4);
        ax += v.x; ay += v.y; az += v.z;
      }
      const float c = fmaxf((float)(j1 - j0), 1.f);
      ax = fminf(fmaxf(ax / c, -COORD_MAX), COORD_MAX);
      ay = fminf(fmaxf(ay / c, -COORD_MAX), COORD_MAX);
      az = fminf(fmaxf(az / c, -COORD_MAX), COORD_MAX);
      outTC[n * 3 + 0] = tgtC[n * 3 + 0] + ax;
      outTC[n * 3 + 1] = tgtC[n * 3 + 1] + ay;
      outTC[n * 3 + 2] = tgtC[n * 3 + 2] + az;
    }
    return;
  }

  const float* __restrict__ feat = J.feat[job];
  const float* __restrict__ agg = J.agg[job];
  const unsigned short* __restrict__ w1p = J.w1p[job];
  const float* __restrict__ b1 = J.b1[job];
  const unsigned short* __restrict__ w2p = J.w2p[job];
  const float* __restrict__ b2 = J.b2[job];
  float* __restrict__ outp = J.outp[job];

  const int n0 = blockIdx.x * TILE_N;

  for (int s = tid; s < 64 * 64; s += 256) {
    const int row = s >> 6;
    const int half = (s >> 5) & 1;
    const int c4 = (s & 31) * 4;
    const int node = n0 + row;
    float4 v = {0.f, 0.f, 0.f, 0.f};
    if (node < N)
      v = reinterpret_cast<const float4*>((half ? agg : feat) + (size_t)node * 128)[s & 31];
    *reinterpret_cast<uint2*>(&sIn[row * LDN + half * 128 + c4]) =
        uint2{cvtpk(v.x, v.y), cvtpk(v.z, v.w)};
  }
  __syncthreads();

  const int lane = tid & 63;
  const int wid = tid >> 6;
  const int rowBase = wid * 16;
  const int r16 = lane & 15;
  const int g4 = lane >> 4;

  f32x4 acc[8];
#pragma unroll
  for (int ct = 0; ct < 8; ++ct) acc[ct] = f32x4{0.f, 0.f, 0.f, 0.f};
#pragma unroll
  for (int ks = 0; ks < 8; ++ks) {
    const short8 a = *reinterpret_cast<const short8*>(
        &sIn[(rowBase + r16) * LDN + ks * 32 + g4 * 8]);
#pragma unroll
    for (int ct = 0; ct < 8; ++ct) {
      const short8 b = *reinterpret_cast<const short8*>(
          w1p + ((size_t)(ks * 8 + ct) * 64 + lane) * 8);
      acc[ct] = mfma16(a, b, acc[ct]);
    }
  }

  __syncthreads();  // all waves done reading sIn; sH2 (alias) writes follow

#pragma unroll
  for (int ct = 0; ct < 8; ct += 2) {
    const int col0 = ct * 16 + r16;
    const int col1 = col0 + 16;
    const float bias0 = b1[col0];
    const float bias1 = b1[col1];
#pragma unroll
    for (int r = 0; r < 4; ++r) {
      const int row = rowBase + g4 * 4 + r;
      const unsigned pk = cvtpk(silu_(acc[ct][r] + bias0), silu_(acc[ct + 1][r] + bias1));
      sH2[row * LDH + col0] = (unsigned short)pk;
      sH2[row * LDH + col1] = (unsigned short)(pk >> 16);
    }
  }

  f32x4 acc2[8];
#pragma unroll
  for (int ct = 0; ct < 8; ++ct) acc2[ct] = f32x4{0.f, 0.f, 0.f, 0.f};
#pragma unroll
  for (int ks = 0; ks < 4; ++ks) {
    const short8 a = *reinterpret_cast<const short8*>(
        &sH2[(rowBase + r16) * LDH + ks * 32 + g4 * 8]);
#pragma unroll
    for (int ct = 0; ct < 8; ++ct) {
      const short8 b = *reinterpret_cast<const short8*>(
          w2p + ((size_t)(ks * 8 + ct) * 64 + lane) * 8);
      acc2[ct] = mfma16(a, b, acc2[ct]);
    }
  }

#pragma unroll
  for (int ct = 0; ct < 8; ++ct) {
    const int col = ct * 16 + r16;
    const float bias = b2[col];
#pragma unroll
    for (int r = 0; r < 4; ++r) {
      const int node = n0 + rowBase + g4 * 4 + r;
      if (node < N)
        outp[(size_t)node * 128 + col] = feat[(size_t)node * 128 + col] + acc2[ct][r] + bias;
    }
  }
}

extern "C" void kernel_launch(void* const* d_in, const int* in_sizes, int n_in,
                              void* d_out, int out_size, void* d_ws, size_t ws_size,
                              hipStream_t stream) {
  const float* srcF = (const float*)d_in[0];
  const float* tgtF = (const float*)d_in[1];
  const float* srcC = (const float*)d_in[2];
  const float* tgtC = (const float*)d_in[3];
  const int* eSrc = (const int*)d_in[4];
  const int* eTgt = (const int*)d_in[5];
  const float* w1_s2t = (const float*)d_in[6];
  const float* b1_s2t = (const float*)d_in[7];
  const float* w2_s2t = (const float*)d_in[8];
  const float* b2_s2t = (const float*)d_in[9];
  const float* w1_t2s = (const float*)d_in[10];
  const float* b1_t2s = (const float*)d_in[11];
  const float* w2_t2s = (const float*)d_in[12];
  const float* b2_t2s = (const float*)d_in[13];
  const float* wg_s2t = (const float*)d_in[14];
  const float* bg_s2t = (const float*)d_in[15];
  const float* wg_t2s = (const float*)d_in[16];
  const float* bg_t2s = (const float*)d_in[17];
  const float* wc1 = (const float*)d_in[18];
  const float* bc1 = (const float*)d_in[19];
  const float* wc2 = (const float*)d_in[20];
  const float* wn1_t = (const float*)d_in[21];
  const float* bn1_t = (const float*)d_in[22];
  const float* wn2_t = (const float*)d_in[23];
  const float* bn2_t = (const float*)d_in[24];
  const float* wn1_s = (const float*)d_in[25];
  const float* bn1_s = (const float*)d_in[26];
  const float* wn2_s = (const float*)d_in[27];
  const float* bn2_s = (const float*)d_in[28];

  char* ws = (char*)d_ws;
  size_t off = 0;
  auto take = [&](size_t bytes) -> char* {
    char* p = ws + off;
    off = (off + bytes + 255) & ~(size_t)255;
    return p;
  };
  float* aggA = (float*)take((size_t)NN * 128 * 4);   // zeroed in prep (contiguous w/ aggB)
  float* aggB = (float*)take((size_t)NN * 128 * 4);
  float* wtBuf = (float*)take((size_t)NEDGE * 4 * 4);
  unsigned short* S1A = (unsigned short*)take((size_t)NN * 128 * 2);
  unsigned short* T1A = (unsigned short*)take((size_t)NN * 128 * 2);
  unsigned short* S1B = (unsigned short*)take((size_t)NN * 128 * 2);
  unsigned short* T1B = (unsigned short*)take((size_t)NN * 128 * 2);
  unsigned short* w1tA = (unsigned short*)take(4 * 4096 * 2);
  unsigned short* w1mA = (unsigned short*)take(4 * 4096 * 2);
  unsigned short* w1tB = (unsigned short*)take(4 * 4096 * 2);
  unsigned short* w1mB = (unsigned short*)take(4 * 4096 * 2);
  unsigned short* w2pA = (unsigned short*)take(4 * 4096 * 2);
  unsigned short* w2pB = (unsigned short*)take(4 * 4096 * 2);
  unsigned short* wc1p = (unsigned short*)take(4 * 4096 * 2);
  unsigned short* wn1pt = (unsigned short*)take(8 * 4096 * 2);
  unsigned short* wn2pt = (unsigned short*)take(4 * 4096 * 2);
  unsigned short* wn1ps = (unsigned short*)take(8 * 4096 * 2);
  unsigned short* wn2ps = (unsigned short*)take(4 * 4096 * 2);
  int* cntT = (int*)take((size_t)NN * 4);
  int* cntS = (int*)take((size_t)NN * 4);
  const char* cntZeroStart = (const char*)cntT;
  const size_t cntZeroBytes = (size_t)((char*)cntS + NN * 4 - (char*)cntT);
  int* rowptrT = (int*)take((size_t)(NN + 1) * 4);
  int* rowptrS = (int*)take((size_t)(NN + 1) * 4);
  int* offT = (int*)take((size_t)NN * 4);
  int* offS = (int*)take((size_t)NN * 4);
  int2* stT = (int2*)take((size_t)NEDGE * 8);
  int2* stS = (int2*)take((size_t)NEDGE * 8);

  hipMemsetAsync((void*)cntZeroStart, 0, cntZeroBytes, stream);

  PackJobs PJ;
  PJ.w[0] = w1_s2t;             PJ.o[0] = w1tA;  PJ.kreal[0] = 128; PJ.nk[0] = 4;
  PJ.w[1] = w1_s2t + 128 * 128; PJ.o[1] = w1mA;  PJ.kreal[1] = 128; PJ.nk[1] = 4;
  PJ.w[2] = w1_t2s;             PJ.o[2] = w1tB;  PJ.kreal[2] = 128; PJ.nk[2] = 4;
  PJ.w[3] = w1_t2s + 128 * 128; PJ.o[3] = w1mB;  PJ.kreal[3] = 128; PJ.nk[3] = 4;
  PJ.w[4] = w2_s2t;             PJ.o[4] = w2pA;  PJ.kreal[4] = 128; PJ.nk[4] = 4;
  PJ.w[5] = w2_t2s;             PJ.o[5] = w2pB;  PJ.kreal[5] = 128; PJ.nk[5] = 4;
  PJ.w[6] = wc1;                PJ.o[6] = wc1p;  PJ.kreal[6] = 128; PJ.nk[6] = 4;
  PJ.w[7] = wn1_t;              PJ.o[7] = wn1pt; PJ.kreal[7] = 256; PJ.nk[7] = 8;
  PJ.w[8] = wn2_t;              PJ.o[8] = wn2pt; PJ.kreal[8] = 128; PJ.nk[8] = 4;
  PJ.w[9] = wn1_s;              PJ.o[9] = wn1ps; PJ.kreal[9] = 256; PJ.nk[9] = 8;
  PJ.w[10] = wn2_s;             PJ.o[10] = wn2ps; PJ.kreal[10] = 128; PJ.nk[10] = 4;
  egnn_prep<<<dim3(1250, 3), 256, 0, stream>>>(PJ, eTgt, eSrc, cntT, cntS, aggA);

  PreJobs PR;
  PR.x[0] = srcF; PR.wA[0] = w1tA; PR.wB[0] = w1tB;
  PR.biasA[0] = nullptr; PR.biasB[0] = nullptr;
  PR.oA[0] = S1A; PR.oB[0] = S1B;
  PR.x[1] = tgtF; PR.wA[1] = w1mA; PR.wB[1] = w1mB;
  PR.biasA[1] = b1_s2t; PR.biasB[1] = b1_t2s;
  PR.oA[1] = T1A; PR.oB[1] = T1B;
  egnn_pre<<<dim3(313, 3), 256, 0, stream>>>(
      PR, NN, cntT, rowptrT, offT, cntS, rowptrS, offS);

  egnn_scatter<<<NEDGE / 256, 256, 0, stream>>>(eTgt, eSrc, offT, offS, stT, stS);

  float* outSrc = (float*)d_out;
  float* outTgt = outSrc + (size_t)NN * 128;
  float* outSC  = outTgt + (size_t)NN * 128;
  float* outTC  = outSC + (size_t)NN * 3;

  egnn_edge<<<dim3(NEDGE / 128, 2), 256, 0, stream>>>(
      S1A, T1A, S1B, T1B, srcC, tgtC, stT, stS,
      w1_s2t, w1_t2s,
      w2pA, b2_s2t, wg_s2t, bg_s2t,
      w2pB, b2_t2s, wg_t2s, bg_t2s,
      wc1p, bc1, wc2, aggA, aggB, wtBuf);

  NodeJobs NJ;
  NJ.feat[0] = tgtF; NJ.agg[0] = aggA;
  NJ.w1p[0] = wn1pt; NJ.b1[0] = bn1_t; NJ.w2p[0] = wn2pt; NJ.b2[0] = bn2_t;
  NJ.outp[0] = outTgt;
  NJ.feat[1] = srcF; NJ.agg[1] = aggB;
  NJ.w1p[1] = wn1ps; NJ.b1[1] = bn1_s; NJ.w2p[1] = wn2ps; NJ.b2[1] = bn2_s;
  NJ.outp[1] = outSrc;

  const int nodeBlocks = (NN + TILE_N - 1) / TILE_N;
  egnn_node<<<dim3(nodeBlocks, 3), 256, 0, stream>>>(
      NJ, NN, srcC, tgtC, wtBuf, rowptrT, outSC, outTC);
}

// Round 14
// 277.906 us; speedup vs baseline: 1.0169x; 1.0169x over previous
//
#include <hip/hip_runtime.h>

#define NN 20000
#define NEDGE 320000
#define COORD_MAX 10.0f

#define LDH 136    // ushort stride (272B, 16B-aligned)
#define TILE_N 64
#define LDN  264   // node kernel input stride (K=256)

typedef __attribute__((ext_vector_type(4))) float f32x4;
typedef __attribute__((ext_vector_type(8))) short short8;
typedef __attribute__((ext_vector_type(8))) __bf16 bf16x8;

static __device__ __forceinline__ f32x4 mfma16(short8 a, short8 b, f32x4 c) {
  return __builtin_amdgcn_mfma_f32_16x16x32_bf16(
      __builtin_bit_cast(bf16x8, a), __builtin_bit_cast(bf16x8, b), c, 0, 0, 0);
}
static __device__ __forceinline__ float bf2f(unsigned short u) {
  unsigned x = ((unsigned)u) << 16;
  return __builtin_bit_cast(float, x);
}
// packed f32x2 -> bf16x2 (RNE), 1 VALU op (gfx950)
static __device__ __forceinline__ unsigned cvtpk(float lo, float hi) {
  unsigned r;
  asm("v_cvt_pk_bf16_f32 %0, %1, %2" : "=v"(r) : "v"(lo), "v"(hi));
  return r;
}
static __device__ __forceinline__ float sigm(float x) {
  return __builtin_amdgcn_rcpf(1.f + __expf(-x));
}
static __device__ __forceinline__ float silu_(float x) { return x * sigm(x); }

// ---------------------------------------------------------------------------
// Prep uber-kernel, grid (1250, 3):
// y=0: edge histogram; y=1: zero agg accumulators; y=2: the 11 weight packs.
// ---------------------------------------------------------------------------
struct PackJobs {
  const float* w[11];
  unsigned short* o[11];
  int kreal[11];
  int nk[11];
};

__global__ void egnn_prep(PackJobs J,
                          const int* __restrict__ eTgt, const int* __restrict__ eSrc,
                          int* __restrict__ cntT, int* __restrict__ cntS,
                          float* __restrict__ aggZero /* 2*NN*128 floats */) {
  const int y = blockIdx.y;
  const int tid = threadIdx.x;
  if (y == 0) {
    const int idx = blockIdx.x * 256 + tid;
    if (idx < NEDGE) {
      atomicAdd(&cntT[eTgt[idx]], 1);
      atomicAdd(&cntS[eSrc[idx]], 1);
    }
  } else if (y == 1) {
    float4* p = reinterpret_cast<float4*>(aggZero);
    const int total = 2 * NN * 128 / 4;
    for (int k = blockIdx.x * 256 + tid; k < total; k += 1250 * 256)
      p[k] = float4{0.f, 0.f, 0.f, 0.f};
  } else {
    int gidx = blockIdx.x;
    int j = 0, base = 0;
    while (j < 11 && gidx >= base + J.nk[j] * 2) { base += J.nk[j] * 2; ++j; }
    if (j >= 11) return;
    const int idx = (gidx - base) * 256 + tid;
    const float* w = J.w[j];
    const int kreal = J.kreal[j];
    const int lane = idx & 63;
    const int ct = (idx >> 6) & 7;
    const int kstep = idx >> 9;
    const int col = ct * 16 + (lane & 15);
    const int k0 = kstep * 32 + (lane >> 4) * 8;
    float v[8];
#pragma unroll
    for (int k = 0; k < 8; ++k) {
      int kk = k0 + k;
      v[k] = (kk < kreal) ? w[(size_t)kk * 128 + col] : 0.f;
    }
    uint4 pk = {cvtpk(v[0], v[1]), cvtpk(v[2], v[3]),
                cvtpk(v[4], v[5]), cvtpk(v[6], v[7])};
    reinterpret_cast<uint4*>(J.o[j])[idx] = pk;
  }
}

// ---------------------------------------------------------------------------
// Precompute (+ fused scan as job 2):
// job0 (src): S1A = srcF@w1topA, S1B = srcF@w1topB.
// job1 (tgt): T1A = tgtF@w1midA + b1A, T1B = ... + b1B.
// job2, blockIdx.x<2: exclusive scan of cntT/cntS -> rowptr + off.
// ---------------------------------------------------------------------------
struct PreJobs {
  const float* x[2];
  const unsigned short* wA[2];
  const unsigned short* wB[2];
  const float* biasA[2];   // null -> none
  const float* biasB[2];
  unsigned short* oA[2];
  unsigned short* oB[2];
};

__global__ __launch_bounds__(256, 4) void egnn_pre(
    PreJobs J, int N,
    const int* __restrict__ c0, int* __restrict__ r0, int* __restrict__ o0,
    const int* __restrict__ c1, int* __restrict__ r1, int* __restrict__ o1) {
  __shared__ __align__(16) unsigned short sX[64 * LDH];
  __shared__ int sums[256];
  const int job = blockIdx.y;
  const int tid = threadIdx.x;

  if (job == 2) {
    if (blockIdx.x >= 2) return;
    const int* cnt = blockIdx.x ? c1 : c0;
    int* rp = blockIdx.x ? r1 : r0;
    int* oc = blockIdx.x ? o1 : o0;
    const int chunk = (NN + 255) / 256;
    const int i0 = tid * chunk;
    int local = 0;
    for (int k = 0; k < chunk; ++k) {
      const int i = i0 + k;
      if (i < NN) local += cnt[i];
    }
    sums[tid] = local;
    __syncthreads();
    for (int s = 1; s < 256; s <<= 1) {
      int v = (tid >= s) ? sums[tid - s] : 0;
      __syncthreads();
      sums[tid] += v;
      __syncthreads();
    }
    int run = (tid == 0) ? 0 : sums[tid - 1];
    for (int k = 0; k < chunk; ++k) {
      const int i = i0 + k;
      if (i < NN) { rp[i] = run; oc[i] = run; run += cnt[i]; }
    }
    if (tid == 255) rp[NN] = sums[255];
    return;
  }

  const float* __restrict__ X = J.x[job];
  const int n0 = blockIdx.x * 64;

  for (int s = tid; s < 64 * 32; s += 256) {
    const int row = s >> 5;
    const int c4 = (s & 31) * 4;
    const int node = n0 + row;
    float4 v = {0.f, 0.f, 0.f, 0.f};
    if (node < N) v = reinterpret_cast<const float4*>(X + (size_t)node * 128)[s & 31];
    *reinterpret_cast<uint2*>(&sX[row * LDH + c4]) =
        uint2{cvtpk(v.x, v.y), cvtpk(v.z, v.w)};
  }
  __syncthreads();

  const int lane = tid & 63, wid = tid >> 6;
  const int r16 = lane & 15, g4 = lane >> 4;
  const int rowBase = wid * 16;

#pragma unroll 1
  for (int half = 0; half < 2; ++half) {
    const unsigned short* __restrict__ W = half ? J.wB[job] : J.wA[job];
    const float* __restrict__ bias = half ? J.biasB[job] : J.biasA[job];
    unsigned short* __restrict__ O = half ? J.oB[job] : J.oA[job];
    f32x4 acc[8];
#pragma unroll
    for (int ct = 0; ct < 8; ++ct) acc[ct] = f32x4{0.f, 0.f, 0.f, 0.f};
#pragma unroll
    for (int ks = 0; ks < 4; ++ks) {
      const short8 a = *reinterpret_cast<const short8*>(
          &sX[(rowBase + r16) * LDH + ks * 32 + g4 * 8]);
#pragma unroll
      for (int ct = 0; ct < 8; ++ct) {
        const short8 b = *reinterpret_cast<const short8*>(
            W + ((size_t)(ks * 8 + ct) * 64 + lane) * 8);
        acc[ct] = mfma16(a, b, acc[ct]);
      }
    }
#pragma unroll
    for (int ct = 0; ct < 8; ct += 2) {
      const int col0 = ct * 16 + r16;
      const int col1 = col0 + 16;
      const float bv0 = bias ? bias[col0] : 0.f;
      const float bv1 = bias ? bias[col1] : 0.f;
#pragma unroll
      for (int r = 0; r < 4; ++r) {
        const int node = n0 + rowBase + g4 * 4 + r;
        if (node < N) {
          const unsigned pk = cvtpk(acc[ct][r] + bv0, acc[ct + 1][r] + bv1);
          O[(size_t)node * 128 + col0] = (unsigned short)pk;
          O[(size_t)node * 128 + col1] = (unsigned short)(pk >> 16);
        }
      }
    }
  }
}

// ---------------------------------------------------------------------------
// Scatter: write SORTED (s,t) pairs directly.
// ---------------------------------------------------------------------------
__global__ void egnn_scatter(const int* __restrict__ eTgt, const int* __restrict__ eSrc,
                             int* __restrict__ offT, int* __restrict__ offS,
                             int2* __restrict__ stT, int2* __restrict__ stS) {
  const int e = blockIdx.x * 256 + threadIdx.x;
  if (e < NEDGE) {
    const int s = eSrc[e], t = eTgt[e];
    stT[atomicAdd(&offT[t], 1)] = int2{s, t};
    stS[atomicAdd(&offS[s], 1)] = int2{s, t};
  }
}

// ---------------------------------------------------------------------------
// Fused edge kernel, sorted order (round-10/12 structure — proven best).
// 128 edges/block, 4 waves x 32 edges, dir = blockIdx.y.
// h-build with 16-load register prefetch (16B gathers).
// dir0: scalar-transposed stash (coord GEMM A-frags) + standard segreduce.
// dir1: packed col'-layout stash (16B writes) + permuted segreduce.
// Interior segments plain store, boundary atomics.
// ---------------------------------------------------------------------------
__global__ __launch_bounds__(256, 4) void egnn_edge(
    const unsigned short* __restrict__ S1A, const unsigned short* __restrict__ T1A,
    const unsigned short* __restrict__ S1B, const unsigned short* __restrict__ T1B,
    const float* __restrict__ srcC, const float* __restrict__ tgtC,
    const int2* __restrict__ stT, const int2* __restrict__ stS,
    const float* __restrict__ w1A, const float* __restrict__ w1B,  // radial rows
    const unsigned short* __restrict__ w2pA, const float* __restrict__ b2A,
    const float* __restrict__ wgA, const float* __restrict__ bgA,
    const unsigned short* __restrict__ w2pB, const float* __restrict__ b2B,
    const float* __restrict__ wgB, const float* __restrict__ bgB,
    const unsigned short* __restrict__ wc1p, const float* __restrict__ bc1,
    const float* __restrict__ wc2,
    float* __restrict__ aggA, float* __restrict__ aggB,
    float* __restrict__ wtBuf)
{
  __shared__ __align__(16) unsigned short sH[4][32 * LDH];  // 34816 B
  __shared__ float sCD[128 * 3];
  __shared__ float sRad[128];
  __shared__ int sS[128];
  __shared__ int sT[128];

  const int dir = blockIdx.y;
  const int tid = threadIdx.x;
  const int j0 = blockIdx.x * 128;

  if (tid < 128) {
    const int2 st = (dir ? stS : stT)[j0 + tid];
    const int s = st.x, t = st.y;
    sS[tid] = s; sT[tid] = t;
    const float dx = tgtC[t * 3 + 0] - srcC[s * 3 + 0];
    const float dy = tgtC[t * 3 + 1] - srcC[s * 3 + 1];
    const float dz = tgtC[t * 3 + 2] - srcC[s * 3 + 2];
    if (dir == 0) {
      sCD[tid * 3 + 0] = dx; sCD[tid * 3 + 1] = dy; sCD[tid * 3 + 2] = dz;
    }
    sRad[tid] = dx * dx + dy * dy + dz * dz;
  }
  __syncthreads();

  const int lane = tid & 63, wid = tid >> 6;
  const int r16 = lane & 15, g4 = lane >> 4;
  const int we = wid * 32;
  const int c8 = (lane & 15) * 8;   // 16B gather column offset
  const int r4 = lane >> 4;         // 0..3: row within 4-row group
  const int c2 = lane * 2;

  const unsigned short* __restrict__ S1 = dir ? S1B : S1A;
  const unsigned short* __restrict__ T1 = dir ? T1B : T1A;  // bias folded in
  const float* w1 = dir ? w1B : w1A;
  const float4 wr0 = *reinterpret_cast<const float4*>(w1 + 256 * 128 + c8);
  const float4 wr1 = *reinterpret_cast<const float4*>(w1 + 256 * 128 + c8 + 4);
  const float* b2 = dir ? b2B : b2A;
  const float* wg = dir ? wgB : wgA;
  const float bg = dir ? bgB[0] : bgA[0];
  const int* __restrict__ nids = dir ? sS : sT;
  float* __restrict__ agg = dir ? aggB : aggA;

  unsigned short* hT = sH[wid];

  // ---- h-build: issue ALL 16 gathers first (register prefetch), then compute
  {
    short8 gA[2][4], gB[2][4];
#pragma unroll
    for (int c = 0; c < 2; ++c)
#pragma unroll
      for (int i = 0; i < 4; ++i) {
        const int row = (c * 4 + i) * 4 + r4;
        const int e = we + row;
        gA[c][i] = *reinterpret_cast<const short8*>(S1 + (size_t)sS[e] * 128 + c8);
        gB[c][i] = *reinterpret_cast<const short8*>(T1 + (size_t)sT[e] * 128 + c8);
      }
#pragma unroll
    for (int c = 0; c < 2; ++c)
#pragma unroll
      for (int i = 0; i < 4; ++i) {
        const int row = (c * 4 + i) * 4 + r4;
        const int e = we + row;
        const float rad = sRad[e];
        union { short8 v; unsigned short u[8]; } a, b;
        a.v = gA[c][i]; b.v = gB[c][i];
        const float f0 = silu_(bf2f(a.u[0]) + bf2f(b.u[0]) + rad * wr0.x);
        const float f1 = silu_(bf2f(a.u[1]) + bf2f(b.u[1]) + rad * wr0.y);
        const float f2 = silu_(bf2f(a.u[2]) + bf2f(b.u[2]) + rad * wr0.z);
        const float f3 = silu_(bf2f(a.u[3]) + bf2f(b.u[3]) + rad * wr0.w);
        const float f4 = silu_(bf2f(a.u[4]) + bf2f(b.u[4]) + rad * wr1.x);
        const float f5 = silu_(bf2f(a.u[5]) + bf2f(b.u[5]) + rad * wr1.y);
        const float f6 = silu_(bf2f(a.u[6]) + bf2f(b.u[6]) + rad * wr1.z);
        const float f7 = silu_(bf2f(a.u[7]) + bf2f(b.u[7]) + rad * wr1.w);
        *reinterpret_cast<uint4*>(&hT[row * LDH + c8]) =
            uint4{cvtpk(f0, f1), cvtpk(f2, f3), cvtpk(f4, f5), cvtpk(f6, f7)};
      }
  }

  // ---- GEMM2: 2 row-tiles x [16x128] @ [128x128]
  const unsigned short* w2p = dir ? w2pB : w2pA;
  f32x4 acc[2][8];
#pragma unroll
  for (int rt = 0; rt < 2; ++rt)
#pragma unroll
    for (int ct = 0; ct < 8; ++ct) acc[rt][ct] = f32x4{0.f, 0.f, 0.f, 0.f};
#pragma unroll
  for (int ks = 0; ks < 4; ++ks) {
    short8 a[2];
#pragma unroll
    for (int rt = 0; rt < 2; ++rt)
      a[rt] = *reinterpret_cast<const short8*>(
          &hT[(rt * 16 + r16) * LDH + ks * 32 + g4 * 8]);
#pragma unroll
    for (int ct = 0; ct < 8; ++ct) {
      const short8 b = *reinterpret_cast<const short8*>(
          w2p + ((size_t)(ks * 8 + ct) * 64 + lane) * 8);
#pragma unroll
      for (int rt = 0; rt < 2; ++rt) acc[rt][ct] = mfma16(a[rt], b, acc[rt][ct]);
    }
  }

  // ---- bias + SiLU + gate
  float part[2][4];
#pragma unroll
  for (int rt = 0; rt < 2; ++rt)
#pragma unroll
    for (int r = 0; r < 4; ++r) part[rt][r] = 0.f;
#pragma unroll
  for (int ct = 0; ct < 8; ++ct) {
    const float b2v = b2[ct * 16 + r16];
    const float wgv = wg[ct * 16 + r16];
#pragma unroll
    for (int rt = 0; rt < 2; ++rt)
#pragma unroll
      for (int r = 0; r < 4; ++r) {
        const float e = silu_(acc[rt][ct][r] + b2v);
        acc[rt][ct][r] = e;
        part[rt][r] += e * wgv;
      }
  }
#pragma unroll
  for (int m = 1; m < 16; m <<= 1)
#pragma unroll
    for (int rt = 0; rt < 2; ++rt)
#pragma unroll
      for (int r = 0; r < 4; ++r) part[rt][r] += __shfl_xor(part[rt][r], m, 64);
#pragma unroll
  for (int rt = 0; rt < 2; ++rt)
#pragma unroll
    for (int r = 0; r < 4; ++r) {
      const float gate = sigm(part[rt][r] + bg);
#pragma unroll
      for (int ct = 0; ct < 8; ++ct) acc[rt][ct][r] *= gate;
    }

  if (dir == 0) {
    // ---- scalar-transposed stash (row = edge, col = TRUE feature), cvtpk-paired
#pragma unroll
    for (int rt = 0; rt < 2; ++rt)
#pragma unroll
      for (int ct = 0; ct < 8; ct += 2)
#pragma unroll
        for (int r = 0; r < 4; ++r) {
          const int row = rt * 16 + g4 * 4 + r;
          const unsigned pk = cvtpk(acc[rt][ct][r], acc[rt][ct + 1][r]);
          hT[row * LDH + ct * 16 + r16] = (unsigned short)pk;
          hT[row * LDH + (ct + 1) * 16 + r16] = (unsigned short)(pk >> 16);
        }

    // ---- coord GEMM on gated e_s2t
    f32x4 ac[2][8];
#pragma unroll
    for (int rt = 0; rt < 2; ++rt)
#pragma unroll
      for (int ct = 0; ct < 8; ++ct) ac[rt][ct] = f32x4{0.f, 0.f, 0.f, 0.f};
#pragma unroll
    for (int ks = 0; ks < 4; ++ks) {
      short8 a[2];
#pragma unroll
      for (int rt = 0; rt < 2; ++rt)
        a[rt] = *reinterpret_cast<const short8*>(
            &hT[(rt * 16 + r16) * LDH + ks * 32 + g4 * 8]);
#pragma unroll
      for (int ct = 0; ct < 8; ++ct) {
        const short8 b = *reinterpret_cast<const short8*>(
            wc1p + ((size_t)(ks * 8 + ct) * 64 + lane) * 8);
#pragma unroll
        for (int rt = 0; rt < 2; ++rt) ac[rt][ct] = mfma16(a[rt], b, ac[rt][ct]);
      }
    }
    float pc[2][4];
#pragma unroll
    for (int rt = 0; rt < 2; ++rt)
#pragma unroll
      for (int r = 0; r < 4; ++r) pc[rt][r] = 0.f;
#pragma unroll
    for (int ct = 0; ct < 8; ++ct) {
      const float bcv = bc1[ct * 16 + r16];
      const float w2v = wc2[ct * 16 + r16];
#pragma unroll
      for (int rt = 0; rt < 2; ++rt)
#pragma unroll
        for (int r = 0; r < 4; ++r)
          pc[rt][r] += silu_(ac[rt][ct][r] + bcv) * w2v;
    }
#pragma unroll
    for (int m = 1; m < 16; m <<= 1)
#pragma unroll
      for (int rt = 0; rt < 2; ++rt)
#pragma unroll
        for (int r = 0; r < 4; ++r) pc[rt][r] += __shfl_xor(pc[rt][r], m, 64);

#pragma unroll
    for (int rt = 0; rt < 2; ++rt)
#pragma unroll
      for (int r = 0; r < 4; ++r) {
        if (r16 == 0) {
          const int el = we + rt * 16 + g4 * 4 + r;
          const float p = pc[rt][r];
          const float4 w = {sCD[el * 3 + 0] * p, sCD[el * 3 + 1] * p,
                            sCD[el * 3 + 2] * p, 0.f};
          *reinterpret_cast<float4*>(wtBuf + (size_t)(j0 + el) * 4) = w;
        }
      }

    // ---- standard segreduce (true-col layout): lane owns cols c2, c2+1
    float s0 = 0.f, s1 = 0.f;
    int curNode = nids[we];
    int segStart = 0;
#pragma unroll 4
    for (int row = 0; row < 32; ++row) {
      const ushort2 v = *reinterpret_cast<const ushort2*>(&hT[row * LDH + c2]);
      s0 += bf2f(v.x); s1 += bf2f(v.y);
      const int nxt = (row < 31) ? nids[we + row + 1] : -1;
      if (nxt != curNode) {
        float* dst = agg + (size_t)curNode * 128 + c2;
        if (segStart > 0 && row < 31) {
          dst[0] = s0; dst[1] = s1;
        } else {
          atomicAdd(dst, s0);
          atomicAdd(dst + 1, s1);
        }
        s0 = 0.f; s1 = 0.f;
        curNode = nxt; segStart = row + 1;
      }
    }
  } else {
    // ---- packed col'-layout stash: one 16B write per (rt, r)
    // position p = r16*8 + ct  (true col = ct*16 + r16)
#pragma unroll
    for (int rt = 0; rt < 2; ++rt)
#pragma unroll
      for (int r = 0; r < 4; ++r) {
        const int row = rt * 16 + g4 * 4 + r;
        const uint4 pk = {cvtpk(acc[rt][0][r], acc[rt][1][r]),
                          cvtpk(acc[rt][2][r], acc[rt][3][r]),
                          cvtpk(acc[rt][4][r], acc[rt][5][r]),
                          cvtpk(acc[rt][6][r], acc[rt][7][r])};
        *reinterpret_cast<uint4*>(&hT[row * LDH + r16 * 8]) = pk;
      }

    // ---- permuted segreduce: lane reads positions (2*lane, 2*lane+1)
    // true cols: t0 = ((2*lane)&7)*16 + (lane>>2), t1 = t0 + 16
    const int t0 = ((2 * lane) & 7) * 16 + (lane >> 2);
    float s0 = 0.f, s1 = 0.f;
    int curNode = nids[we];
    int segStart = 0;
#pragma unroll 4
    for (int row = 0; row < 32; ++row) {
      const ushort2 v = *reinterpret_cast<const ushort2*>(&hT[row * LDH + c2]);
      s0 += bf2f(v.x); s1 += bf2f(v.y);
      const int nxt = (row < 31) ? nids[we + row + 1] : -1;
      if (nxt != curNode) {
        float* dst = agg + (size_t)curNode * 128;
        if (segStart > 0 && row < 31) {
          dst[t0] = s0; dst[t0 + 16] = s1;
        } else {
          atomicAdd(dst + t0, s0);
          atomicAdd(dst + t0 + 16, s1);
        }
        s0 = 0.f; s1 = 0.f;
        curNode = nxt; segStart = row + 1;
      }
    }
  }
}

// ---------------------------------------------------------------------------
// Node kernel (+ fused coord finalize as job 2). sH2 aliases sIn (barrier
// separates the last sIn read from sH2 writes) -> 33.8 KB LDS, 4 blocks/CU.
// ---------------------------------------------------------------------------
struct NodeJobs {
  const float* feat[2];
  const float* agg[2];
  const unsigned short* w1p[2];
  const float* b1[2];
  const unsigned short* w2p[2];
  const float* b2[2];
  float* outp[2];
};

__global__ __launch_bounds__(256, 4) void egnn_node(
    NodeJobs J, int N,
    const float* __restrict__ srcC, const float* __restrict__ tgtC,
    const float* __restrict__ wt, const int* __restrict__ rp,
    float* __restrict__ outSC, float* __restrict__ outTC) {
  __shared__ __align__(16) unsigned short sIn[TILE_N * LDN];  // 33792 B
  unsigned short* sH2 = sIn;  // aliased; safe after barrier below
  const int job = blockIdx.y;
  const int tid = threadIdx.x;

  if (job == 2) {
    const int n = blockIdx.x * 256 + tid;
    if (n < NN) {
      outSC[n * 3 + 0] = srcC[n * 3 + 0];
      outSC[n * 3 + 1] = srcC[n * 3 + 1];
      outSC[n * 3 + 2] = srcC[n * 3 + 2];
      const int j0 = rp[n], j1 = rp[n + 1];
      float ax = 0.f, ay = 0.f, az = 0.f;
      for (int j = j0; j < j1; ++j) {
        const float4 v = *reinterpret_cast<const float4*>(wt + (size_t)j * 4);
        ax += v.x; ay += v.y; az += v.z;
      }
      const float c = fmaxf((float)(j1 - j0), 1.f);
      ax = fminf(fmaxf(ax / c, -COORD_MAX), COORD_MAX);
      ay = fminf(fmaxf(ay / c, -COORD_MAX), COORD_MAX);
      az = fminf(fmaxf(az / c, -COORD_MAX), COORD_MAX);
      outTC[n * 3 + 0] = tgtC[n * 3 + 0] + ax;
      outTC[n * 3 + 1] = tgtC[n * 3 + 1] + ay;
      outTC[n * 3 + 2] = tgtC[n * 3 + 2] + az;
    }
    return;
  }

  const float* __restrict__ feat = J.feat[job];
  const float* __restrict__ agg = J.agg[job];
  const unsigned short* __restrict__ w1p = J.w1p[job];
  const float* __restrict__ b1 = J.b1[job];
  const unsigned short* __restrict__ w2p = J.w2p[job];
  const float* __restrict__ b2 = J.b2[job];
  float* __restrict__ outp = J.outp[job];

  const int n0 = blockIdx.x * TILE_N;

  for (int s = tid; s < 64 * 64; s += 256) {
    const int row = s >> 6;
    const int half = (s >> 5) & 1;
    const int c4 = (s & 31) * 4;
    const int node = n0 + row;
    float4 v = {0.f, 0.f, 0.f, 0.f};
    if (node < N)
      v = reinterpret_cast<const float4*>((half ? agg : feat) + (size_t)node * 128)[s & 31];
    *reinterpret_cast<uint2*>(&sIn[row * LDN + half * 128 + c4]) =
        uint2{cvtpk(v.x, v.y), cvtpk(v.z, v.w)};
  }
  __syncthreads();

  const int lane = tid & 63;
  const int wid = tid >> 6;
  const int rowBase = wid * 16;
  const int r16 = lane & 15;
  const int g4 = lane >> 4;

  f32x4 acc[8];
#pragma unroll
  for (int ct = 0; ct < 8; ++ct) acc[ct] = f32x4{0.f, 0.f, 0.f, 0.f};
#pragma unroll
  for (int ks = 0; ks < 8; ++ks) {
    const short8 a = *reinterpret_cast<const short8*>(
        &sIn[(rowBase + r16) * LDN + ks * 32 + g4 * 8]);
#pragma unroll
    for (int ct = 0; ct < 8; ++ct) {
      const short8 b = *reinterpret_cast<const short8*>(
          w1p + ((size_t)(ks * 8 + ct) * 64 + lane) * 8);
      acc[ct] = mfma16(a, b, acc[ct]);
    }
  }

  __syncthreads();  // all waves done reading sIn; sH2 (alias) writes follow

#pragma unroll
  for (int ct = 0; ct < 8; ct += 2) {
    const int col0 = ct * 16 + r16;
    const int col1 = col0 + 16;
    const float bias0 = b1[col0];
    const float bias1 = b1[col1];
#pragma unroll
    for (int r = 0; r < 4; ++r) {
      const int row = rowBase + g4 * 4 + r;
      const unsigned pk = cvtpk(silu_(acc[ct][r] + bias0), silu_(acc[ct + 1][r] + bias1));
      sH2[row * LDH + col0] = (unsigned short)pk;
      sH2[row * LDH + col1] = (unsigned short)(pk >> 16);
    }
  }

  f32x4 acc2[8];
#pragma unroll
  for (int ct = 0; ct < 8; ++ct) acc2[ct] = f32x4{0.f, 0.f, 0.f, 0.f};
#pragma unroll
  for (int ks = 0; ks < 4; ++ks) {
    const short8 a = *reinterpret_cast<const short8*>(
        &sH2[(rowBase + r16) * LDH + ks * 32 + g4 * 8]);
#pragma unroll
    for (int ct = 0; ct < 8; ++ct) {
      const short8 b = *reinterpret_cast<const short8*>(
          w2p + ((size_t)(ks * 8 + ct) * 64 + lane) * 8);
      acc2[ct] = mfma16(a, b, acc2[ct]);
    }
  }

#pragma unroll
  for (int ct = 0; ct < 8; ++ct) {
    const int col = ct * 16 + r16;
    const float bias = b2[col];
#pragma unroll
    for (int r = 0; r < 4; ++r) {
      const int node = n0 + rowBase + g4 * 4 + r;
      if (node < N)
        outp[(size_t)node * 128 + col] = feat[(size_t)node * 128 + col] + acc2[ct][r] + bias;
    }
  }
}

extern "C" void kernel_launch(void* const* d_in, const int* in_sizes, int n_in,
                              void* d_out, int out_size, void* d_ws, size_t ws_size,
                              hipStream_t stream) {
  const float* srcF = (const float*)d_in[0];
  const float* tgtF = (const float*)d_in[1];
  const float* srcC = (const float*)d_in[2];
  const float* tgtC = (const float*)d_in[3];
  const int* eSrc = (const int*)d_in[4];
  const int* eTgt = (const int*)d_in[5];
  const float* w1_s2t = (const float*)d_in[6];
  const float* b1_s2t = (const float*)d_in[7];
  const float* w2_s2t = (const float*)d_in[8];
  const float* b2_s2t = (const float*)d_in[9];
  const float* w1_t2s = (const float*)d_in[10];
  const float* b1_t2s = (const float*)d_in[11];
  const float* w2_t2s = (const float*)d_in[12];
  const float* b2_t2s = (const float*)d_in[13];
  const float* wg_s2t = (const float*)d_in[14];
  const float* bg_s2t = (const float*)d_in[15];
  const float* wg_t2s = (const float*)d_in[16];
  const float* bg_t2s = (const float*)d_in[17];
  const float* wc1 = (const float*)d_in[18];
  const float* bc1 = (const float*)d_in[19];
  const float* wc2 = (const float*)d_in[20];
  const float* wn1_t = (const float*)d_in[21];
  const float* bn1_t = (const float*)d_in[22];
  const float* wn2_t = (const float*)d_in[23];
  const float* bn2_t = (const float*)d_in[24];
  const float* wn1_s = (const float*)d_in[25];
  const float* bn1_s = (const float*)d_in[26];
  const float* wn2_s = (const float*)d_in[27];
  const float* bn2_s = (const float*)d_in[28];

  char* ws = (char*)d_ws;
  size_t off = 0;
  auto take = [&](size_t bytes) -> char* {
    char* p = ws + off;
    off = (off + bytes + 255) & ~(size_t)255;
    return p;
  };
  float* aggA = (float*)take((size_t)NN * 128 * 4);   // zeroed in prep (contiguous w/ aggB)
  float* aggB = (float*)take((size_t)NN * 128 * 4);
  float* wtBuf = (float*)take((size_t)NEDGE * 4 * 4);
  unsigned short* S1A = (unsigned short*)take((size_t)NN * 128 * 2);
  unsigned short* T1A = (unsigned short*)take((size_t)NN * 128 * 2);
  unsigned short* S1B = (unsigned short*)take((size_t)NN * 128 * 2);
  unsigned short* T1B = (unsigned short*)take((size_t)NN * 128 * 2);
  unsigned short* w1tA = (unsigned short*)take(4 * 4096 * 2);
  unsigned short* w1mA = (unsigned short*)take(4 * 4096 * 2);
  unsigned short* w1tB = (unsigned short*)take(4 * 4096 * 2);
  unsigned short* w1mB = (unsigned short*)take(4 * 4096 * 2);
  unsigned short* w2pA = (unsigned short*)take(4 * 4096 * 2);
  unsigned short* w2pB = (unsigned short*)take(4 * 4096 * 2);
  unsigned short* wc1p = (unsigned short*)take(4 * 4096 * 2);
  unsigned short* wn1pt = (unsigned short*)take(8 * 4096 * 2);
  unsigned short* wn2pt = (unsigned short*)take(4 * 4096 * 2);
  unsigned short* wn1ps = (unsigned short*)take(8 * 4096 * 2);
  unsigned short* wn2ps = (unsigned short*)take(4 * 4096 * 2);
  int* cntT = (int*)take((size_t)NN * 4);
  int* cntS = (int*)take((size_t)NN * 4);
  const char* cntZeroStart = (const char*)cntT;
  const size_t cntZeroBytes = (size_t)((char*)cntS + NN * 4 - (char*)cntT);
  int* rowptrT = (int*)take((size_t)(NN + 1) * 4);
  int* rowptrS = (int*)take((size_t)(NN + 1) * 4);
  int* offT = (int*)take((size_t)NN * 4);
  int* offS = (int*)take((size_t)NN * 4);
  int2* stT = (int2*)take((size_t)NEDGE * 8);
  int2* stS = (int2*)take((size_t)NEDGE * 8);

  hipMemsetAsync((void*)cntZeroStart, 0, cntZeroBytes, stream);

  PackJobs PJ;
  PJ.w[0] = w1_s2t;             PJ.o[0] = w1tA;  PJ.kreal[0] = 128; PJ.nk[0] = 4;
  PJ.w[1] = w1_s2t + 128 * 128; PJ.o[1] = w1mA;  PJ.kreal[1] = 128; PJ.nk[1] = 4;
  PJ.w[2] = w1_t2s;             PJ.o[2] = w1tB;  PJ.kreal[2] = 128; PJ.nk[2] = 4;
  PJ.w[3] = w1_t2s + 128 * 128; PJ.o[3] = w1mB;  PJ.kreal[3] = 128; PJ.nk[3] = 4;
  PJ.w[4] = w2_s2t;             PJ.o[4] = w2pA;  PJ.kreal[4] = 128; PJ.nk[4] = 4;
  PJ.w[5] = w2_t2s;             PJ.o[5] = w2pB;  PJ.kreal[5] = 128; PJ.nk[5] = 4;
  PJ.w[6] = wc1;                PJ.o[6] = wc1p;  PJ.kreal[6] = 128; PJ.nk[6] = 4;
  PJ.w[7] = wn1_t;              PJ.o[7] = wn1pt; PJ.kreal[7] = 256; PJ.nk[7] = 8;
  PJ.w[8] = wn2_t;              PJ.o[8] = wn2pt; PJ.kreal[8] = 128; PJ.nk[8] = 4;
  PJ.w[9] = wn1_s;              PJ.o[9] = wn1ps; PJ.kreal[9] = 256; PJ.nk[9] = 8;
  PJ.w[10] = wn2_s;             PJ.o[10] = wn2ps; PJ.kreal[10] = 128; PJ.nk[10] = 4;
  egnn_prep<<<dim3(1250, 3), 256, 0, stream>>>(PJ, eTgt, eSrc, cntT, cntS, aggA);

  PreJobs PR;
  PR.x[0] = srcF; PR.wA[0] = w1tA; PR.wB[0] = w1tB;
  PR.biasA[0] = nullptr; PR.biasB[0] = nullptr;
  PR.oA[0] = S1A; PR.oB[0] = S1B;
  PR.x[1] = tgtF; PR.wA[1] = w1mA; PR.wB[1] = w1mB;
  PR.biasA[1] = b1_s2t; PR.biasB[1] = b1_t2s;
  PR.oA[1] = T1A; PR.oB[1] = T1B;
  egnn_pre<<<dim3(313, 3), 256, 0, stream>>>(
      PR, NN, cntT, rowptrT, offT, cntS, rowptrS, offS);

  egnn_scatter<<<NEDGE / 256, 256, 0, stream>>>(eTgt, eSrc, offT, offS, stT, stS);

  float* outSrc = (float*)d_out;
  float* outTgt = outSrc + (size_t)NN * 128;
  float* outSC  = outTgt + (size_t)NN * 128;
  float* outTC  = outSC + (size_t)NN * 3;

  egnn_edge<<<dim3(NEDGE / 128, 2), 256, 0, stream>>>(
      S1A, T1A, S1B, T1B, srcC, tgtC, stT, stS,
      w1_s2t, w1_t2s,
      w2pA, b2_s2t, wg_s2t, bg_s2t,
      w2pB, b2_t2s, wg_t2s, bg_t2s,
      wc1p, bc1, wc2, aggA, aggB, wtBuf);

  NodeJobs NJ;
  NJ.feat[0] = tgtF; NJ.agg[0] = aggA;
  NJ.w1p[0] = wn1pt; NJ.b1[0] = bn1_t; NJ.w2p[0] = wn2pt; NJ.b2[0] = bn2_t;
  NJ.outp[0] = outTgt;
  NJ.feat[1] = srcF; NJ.agg[1] = aggB;
  NJ.w1p[1] = wn1ps; NJ.b1[1] = bn1_s; NJ.w2p[1] = wn2ps; NJ.b2[1] = bn2_s;
  NJ.outp[1] = outSrc;

  const int nodeBlocks = (NN + TILE_N - 1) / TILE_N;
  egnn_node<<<dim3(nodeBlocks, 3), 256, 0, stream>>>(
      NJ, NN, srcC, tgtC, wtBuf, rowptrT, outSC, outTC);
}